// Round 8
// baseline (333.481 us; speedup 1.0000x reference)
//
#include <hip/hip_runtime.h>
#include <hip/hip_bf16.h>
#include <math.h>

#define NEG_SLOPE 0.2f
#define BSH    7          // log2(nodes per bucket)
#define BNODES 128        // nodes per bucket
#define CAP    2560       // max edges per bucket in LDS (mean 2048, 11 sigma)
#define MAXB   1024       // bucket count (covers up to 131072 nodes)
#define NCHUNK 256        // partition chunks
#define CEMAX  6272       // max edges per chunk staged in LDS (CE = 6250)
#define SMEMB  37376      // fused-kernel LDS bytes: part path 37376 > linear 16384

typedef __attribute__((ext_vector_type(8))) short bf16x8;
typedef __attribute__((ext_vector_type(4))) float f32x4;

__device__ __forceinline__ float leaky(float v) { return v >= 0.0f ? v : NEG_SLOPE * v; }
__device__ __forceinline__ int clampi(int v, int lo, int hi) {
    return v < lo ? lo : (v > hi ? hi : v);
}
// decode packed bf16 pair (low word / high word of a uint)
__device__ __forceinline__ float bflo(unsigned u) { return __uint_as_float(u << 16); }
__device__ __forceinline__ float bfhi(unsigned u) { return __uint_as_float(u & 0xFFFF0000u); }
// fp32 -> bf16 round-to-nearest-even
__device__ __forceinline__ unsigned short f2bf(float f) {
    unsigned u = __float_as_uint(f);
    return (unsigned short)((u + 0x7FFFu + ((u >> 16) & 1u)) >> 16);
}
__device__ __forceinline__ bf16x8 pack8(float4 a, float4 b) {
    bf16x8 r;
    r[0] = (short)f2bf(a.x); r[1] = (short)f2bf(a.y);
    r[2] = (short)f2bf(a.z); r[3] = (short)f2bf(a.w);
    r[4] = (short)f2bf(b.x); r[5] = (short)f2bf(b.y);
    r[6] = (short)f2bf(b.z); r[7] = (short)f2bf(b.w);
    return r;
}
// bijective XCD-chunked swizzle (m204): consecutive buckets land on one XCD
__device__ __forceinline__ int xcd_swz(int orig, int nwg) {
    int xcd = orig & 7;
    int i   = orig >> 3;
    int qq  = nwg >> 3, rr = nwg & 7;
    int base = (xcd < rr) ? xcd * (qq + 1) : rr * (qq + 1) + (xcd - rr) * qq;
    return base + i;
}

// K1 (fused): blocks [0, nb_lin) = MFMA linear+epilogue; blocks
// [nb_lin, nb_lin+NCHUNK) = chunk-local edge binning. Data-independent halves
// run concurrently. Wave-0 shfl scan (round 6). Unchanged this round.
__global__ __launch_bounds__(512) void k_fused(
    const float* __restrict__ x, const float* __restrict__ W,
    const float* __restrict__ att_src, const float* __restrict__ att_dst,
    __hip_bfloat16* __restrict__ h, float* __restrict__ a_s,
    float* __restrict__ a_d, const int* __restrict__ ei,
    unsigned* __restrict__ binned, int* __restrict__ offc,
    int N, int E, int CE, int nb_lin)
{
    __shared__ int4 smem4[SMEMB / 16];
    const int tid = threadIdx.x;

    if ((int)blockIdx.x < nb_lin) {
        short* wlds = (short*)smem4;      // 16 frag-sets x 64 lanes x 8 bf16

        for (int idx = tid; idx < 1024; idx += 512) {
            int f = idx >> 6, L = idx & 63;
            int t = f >> 2, k0i = f & 3;
            int kbase = k0i * 32 + (L >> 4) * 8;
            int c = t * 16 + (L & 15);
            unsigned short v[8];
#pragma unroll
            for (int j = 0; j < 8; ++j) v[j] = f2bf(W[(kbase + j) * 64 + c]);
            uint4 p;
            p.x = (unsigned)v[0] | ((unsigned)v[1] << 16);
            p.y = (unsigned)v[2] | ((unsigned)v[3] << 16);
            p.z = (unsigned)v[4] | ((unsigned)v[5] << 16);
            p.w = (unsigned)v[6] | ((unsigned)v[7] << 16);
            ((uint4*)wlds)[idx] = p;
        }
        __syncthreads();

        const int lane = tid & 63;
        const int w    = tid >> 6;
        const int base = blockIdx.x * 128 + w * 16;
        const int m    = lane & 15;
        const int quad = lane >> 4;

        int rowc = min(base + m, N - 1);
        const float4* xr = (const float4*)x + (size_t)rowc * 32;

        bf16x8 afrag[4];
#pragma unroll
        for (int k0i = 0; k0i < 4; ++k0i) {
            float4 f0 = xr[k0i * 8 + quad * 2 + 0];
            float4 f1 = xr[k0i * 8 + quad * 2 + 1];
            afrag[k0i] = pack8(f0, f1);
        }

        f32x4 acc[4];
#pragma unroll
        for (int t = 0; t < 4; ++t) acc[t] = (f32x4){0.f, 0.f, 0.f, 0.f};

        const bf16x8* wf = (const bf16x8*)wlds;
#pragma unroll
        for (int t = 0; t < 4; ++t) {
#pragma unroll
            for (int k0i = 0; k0i < 4; ++k0i) {
                bf16x8 bfr = wf[(t * 4 + k0i) * 64 + lane];
                acc[t] = __builtin_amdgcn_mfma_f32_16x16x32_bf16(afrag[k0i], bfr, acc[t], 0, 0, 0);
            }
        }

        float ps[4] = {0.f, 0.f, 0.f, 0.f};
        float pd[4] = {0.f, 0.f, 0.f, 0.f};
#pragma unroll
        for (int t = 0; t < 4; ++t) {
            float as_c = att_src[t * 16 + m];
            float ad_c = att_dst[t * 16 + m];
#pragma unroll
            for (int q = 0; q < 4; ++q) {
                ps[q] = fmaf(acc[t][q], as_c, ps[q]);
                pd[q] = fmaf(acc[t][q], ad_c, pd[q]);
            }
        }
#pragma unroll
        for (int t = 0; t < 4; ++t) {
#pragma unroll
            for (int q = 0; q < 4; ++q) {
                int n = base + quad * 4 + q;
                if (n < N) h[(size_t)n * 64 + t * 16 + m] = __float2bfloat16(acc[t][q]);
            }
        }
#pragma unroll
        for (int q = 0; q < 4; ++q) {
            ps[q] += __shfl_xor(ps[q], 1, 64);
            ps[q] += __shfl_xor(ps[q], 2, 64);
            ps[q] += __shfl_xor(ps[q], 4, 64);
            ps[q] += __shfl_xor(ps[q], 8, 64);
            pd[q] += __shfl_xor(pd[q], 1, 64);
            pd[q] += __shfl_xor(pd[q], 2, 64);
            pd[q] += __shfl_xor(pd[q], 4, 64);
            pd[q] += __shfl_xor(pd[q], 8, 64);
        }
        if (m == 0) {
#pragma unroll
            for (int q = 0; q < 4; ++q) {
                int n = base + quad * 4 + q;
                if (n < N) { a_s[n] = ps[q]; a_d[n] = pd[q]; }
            }
        }
    } else {
        int* hist = (int*)smem4;              // 1024
        int* off  = hist + MAXB;              // 1024
        int* cur  = off + MAXB;               // 1024
        unsigned* stage = (unsigned*)(cur + MAXB);  // CEMAX

        const int c  = (int)blockIdx.x - nb_lin;
        const int e0 = c * CE;
        const int e1 = min(E, e0 + CE);
        const int ne = e1 - e0;

        for (int i = tid; i < MAXB; i += 512) hist[i] = 0;
        __syncthreads();
        for (int e = e0 + tid; e < e1; e += 512) {
            int dst = clampi(ei[E + e], 0, N - 1);
            atomicAdd(&hist[dst >> BSH], 1);
        }
        __syncthreads();
        // wave 0: exclusive scan of hist[0..1023] -> off, cur (no barriers)
        if (tid < 64) {
            int v[16]; int tsum = 0;
#pragma unroll
            for (int k = 0; k < 16; ++k) { v[k] = hist[tid * 16 + k]; tsum += v[k]; }
            int incl = tsum;
#pragma unroll
            for (int d = 1; d < 64; d <<= 1) {
                int t = __shfl_up(incl, d, 64);
                if (tid >= d) incl += t;
            }
            int run = incl - tsum;
#pragma unroll
            for (int k = 0; k < 16; ++k) {
                off[tid * 16 + k] = run;
                cur[tid * 16 + k] = run;
                run += v[k];
            }
        }
        __syncthreads();
        for (int e = e0 + tid; e < e1; e += 512) {
            int src = clampi(ei[e],     0, N - 1);
            int dst = clampi(ei[E + e], 0, N - 1);
            int pos = atomicAdd(&cur[dst >> BSH], 1);
            stage[clampi(pos, 0, CEMAX - 1)] =
                ((unsigned)(dst & (BNODES - 1)) << 17) | (unsigned)src;
        }
        __syncthreads();
        for (int i = tid; i < ne; i += 512) binned[e0 + i] = stage[i];
        int* oc = offc + (size_t)c * (MAXB + 1);
        for (int i = tid; i < MAXB; i += 512) oc[i] = off[i];
        if (tid == 0) oc[MAXB] = ne;
    }
}

// K2: one block (512 threads, 8 waves) per 128-node bucket.
// Round 8 = round-6 structure + ONE change in Phase B: batch-4 double-buffered
// gather pipeline with __builtin_amdgcn_sched_barrier(0) fences. Three rounds
// (r4/r5/r7) proved the compiler sinks prefetch loads to just-before-use
// (VGPR stayed 32 each time); sched_barrier(0) is a hard fence no instruction
// may cross, so the 4-load cluster must issue before its consume cluster ->
// 4-8 gathers in flight per lane instead of 1.
#define CONS(Uv, wv) \
    acc0 = fmaf(wv, bflo(Uv.x), acc0); \
    acc1 = fmaf(wv, bfhi(Uv.x), acc1); \
    acc2 = fmaf(wv, bflo(Uv.y), acc2); \
    acc3 = fmaf(wv, bfhi(Uv.y), acc3); \
    acc4 = fmaf(wv, bflo(Uv.z), acc4); \
    acc5 = fmaf(wv, bfhi(Uv.z), acc5); \
    acc6 = fmaf(wv, bflo(Uv.w), acc6); \
    acc7 = fmaf(wv, bfhi(Uv.w), acc7);
// guarded load: out-of-range edges carry w=0 (their FMAs are no-ops)
#define LOADG(idx, Uv, wv) \
    if ((idx) < deg) { uint2 _e = ew[s0 + (idx)]; \
        wv = __uint_as_float(_e.y); Uv = h4[(size_t)_e.x * 8 + q]; } \
    else { wv = 0.f; Uv = make_uint4(0u, 0u, 0u, 0u); }

__global__ __launch_bounds__(512, 8) void k_agg(
    const unsigned* __restrict__ binned, const int* __restrict__ offc,
    const float* __restrict__ a_s, const float* __restrict__ a_d,
    const __hip_bfloat16* __restrict__ hm, const float* __restrict__ bias,
    float* __restrict__ out, int N, int CE)
{
    __shared__ int   cnt[BNODES];
    __shared__ int   st[BNODES];
    __shared__ int   cur[BNODES];
    __shared__ float lsum[BNODES];
    __shared__ float wsl[BNODES];
    __shared__ float adl[BNODES];
    __shared__ int   runScan[NCHUNK + 1];
    __shared__ int   gbase[NCHUNK];
    __shared__ unsigned eraw[CAP];
    __shared__ uint2 ew[CAP];          // .x = src node, .y = f32 bits of w

    const int tid   = threadIdx.x;
    const int b     = xcd_swz((int)blockIdx.x, (int)gridDim.x);
    const int nbase = b << BSH;

    if (tid < BNODES) {
        cnt[tid] = 0;
        int n = nbase + tid;
        float as = 0.f, ad = 0.f;
        if (n < N) { as = a_s[n]; ad = a_d[n]; }
        adl[tid] = ad;
        float v = (n < N) ? __expf(leaky(as + ad)) : 0.f;
        wsl[tid]  = v;                 // self-loop weight
        lsum[tid] = v;                 // denominator starts with self loop
    }
    if (tid < NCHUNK) {
        const int* oc = offc + (size_t)tid * (MAXB + 1);
        int o0 = clampi(oc[b],     0, CE);
        int o1 = clampi(oc[b + 1], o0, CE);
        gbase[tid]   = tid * CE + o0;
        runScan[tid] = o1 - o0;        // run length (scanned below)
    }
    __syncthreads();                                   // B1
    // wave 0: exclusive scan of runScan[0..255] in registers
    if (tid < 64) {
        int v0 = runScan[tid * 4 + 0], v1 = runScan[tid * 4 + 1];
        int v2 = runScan[tid * 4 + 2], v3 = runScan[tid * 4 + 3];
        int tsum = v0 + v1 + v2 + v3;
        int incl = tsum;
#pragma unroll
        for (int d = 1; d < 64; d <<= 1) {
            int t = __shfl_up(incl, d, 64);
            if (tid >= d) incl += t;
        }
        int excl = incl - tsum;
        runScan[tid * 4 + 0] = excl;
        runScan[tid * 4 + 1] = excl + v0;
        runScan[tid * 4 + 2] = excl + v0 + v1;
        runScan[tid * 4 + 3] = excl + v0 + v1 + v2;
        if (tid == 63) runScan[NCHUNK] = incl;
    }
    __syncthreads();                                   // B2
    int n_e = runScan[NCHUNK];
    if (n_e > CAP) n_e = CAP;          // statistically never

    // fused: coalesced copy (binary search chunk map) + node histogram
    for (int i = tid; i < n_e; i += 512) {
        int c = 0;
#pragma unroll
        for (int stp = NCHUNK >> 1; stp >= 1; stp >>= 1)
            if (runScan[c + stp] <= i) c += stp;
        unsigned pk = binned[(size_t)gbase[c] + (i - runScan[c])];
        eraw[i] = pk;
        atomicAdd(&cnt[(pk >> 17) & (BNODES - 1)], 1);
    }
    __syncthreads();                                   // B3
    // wave 0: exclusive scan of cnt[0..127] -> st, cur
    if (tid < 64) {
        int v0 = cnt[tid * 2], v1 = cnt[tid * 2 + 1];
        int tsum = v0 + v1;
        int incl = tsum;
#pragma unroll
        for (int d = 1; d < 64; d <<= 1) {
            int t = __shfl_up(incl, d, 64);
            if (tid >= d) incl += t;
        }
        int excl = incl - tsum;
        st[tid * 2]      = excl;      cur[tid * 2]      = excl;
        st[tid * 2 + 1]  = excl + v0; cur[tid * 2 + 1]  = excl + v0;
    }
    __syncthreads();                                   // B4
    // scatter + fused attention weight + denominator (LDS -> LDS)
    for (int i = tid; i < n_e; i += 512) {
        unsigned pk = eraw[i];
        int ld  = (int)(pk >> 17) & (BNODES - 1);
        int src = (int)(pk & 0x1FFFFu);
        float wv = __expf(leaky(a_s[src] + adl[ld]));
        int pos = atomicAdd(&cur[ld], 1);
        if (pos < CAP) ew[pos] = make_uint2((unsigned)src, __float_as_uint(wv));
        atomicAdd(&lsum[ld], wv);
    }
    __syncthreads();                                   // B5

    // Phase B: lane = (node-slot p = lane>>3, octet q = lane&7)
    const int lane = tid & 63;
    const int w    = tid >> 6;       // wave 0..7
    const int q    = lane & 7;       // feature octet: features 8q..8q+7
    const int p    = lane >> 3;      // node slot 0..7
    const uint4*  h4 = (const uint4*)hm;
    const float4* b4 = (const float4*)bias;
    const float4 bb0 = b4[2 * q];
    const float4 bb1 = b4[2 * q + 1];

#pragma unroll 1
    for (int t = 0; t < 2; ++t) {
        int ln = t * 64 + w * 8 + p;
        int n  = nbase + ln;
        if (n >= N) continue;
        int deg = cnt[ln];
        int s0  = st[ln];
        if (s0 > CAP) s0 = CAP;            // defensive (never in practice)
        if (deg > CAP - s0) deg = CAP - s0;

        // self-loop contribution (each lane owns its octet exactly once)
        float wself = wsl[ln];
        uint4 U = h4[(size_t)n * 8 + q];
        float acc0 = wself * bflo(U.x), acc1 = wself * bfhi(U.x);
        float acc2 = wself * bflo(U.y), acc3 = wself * bfhi(U.y);
        float acc4 = wself * bflo(U.z), acc5 = wself * bfhi(U.z);
        float acc6 = wself * bflo(U.w), acc7 = wself * bfhi(U.w);

        // batch-4 double-buffered gather pipeline, sched_barrier-pinned
        uint4 UA, UB, UC, UD, VA, VB, VC, VD;
        float wa, wb, wcv, wd, va, vb, vcv, vd;
        LOADG(0, UA, wa); LOADG(1, UB, wb); LOADG(2, UC, wcv); LOADG(3, UD, wd);
#pragma unroll 1
        for (int j = 0; j < deg; j += 8) {
            LOADG(j + 4, VA, va);  LOADG(j + 5, VB, vb);
            LOADG(j + 6, VC, vcv); LOADG(j + 7, VD, vd);
            __builtin_amdgcn_sched_barrier(0);   // loads above stay above
            CONS(UA, wa); CONS(UB, wb); CONS(UC, wcv); CONS(UD, wd);
            LOADG(j + 8,  UA, wa);  LOADG(j + 9,  UB, wb);
            LOADG(j + 10, UC, wcv); LOADG(j + 11, UD, wd);
            __builtin_amdgcn_sched_barrier(0);
            CONS(VA, va); CONS(VB, vb); CONS(VC, vcv); CONS(VD, vd);
        }

        float inv = 1.0f / lsum[ln];
        float4 o0, o1;
        o0.x = bb0.x + acc0 * inv;
        o0.y = bb0.y + acc1 * inv;
        o0.z = bb0.z + acc2 * inv;
        o0.w = bb0.w + acc3 * inv;
        o1.x = bb1.x + acc4 * inv;
        o1.y = bb1.y + acc5 * inv;
        o1.z = bb1.z + acc6 * inv;
        o1.w = bb1.w + acc7 * inv;
        float4* o4 = (float4*)out;
        o4[(size_t)n * 16 + 2 * q + 0] = o0;
        o4[(size_t)n * 16 + 2 * q + 1] = o1;
    }
}

extern "C" void kernel_launch(void* const* d_in, const int* in_sizes, int n_in,
                              void* d_out, int out_size, void* d_ws, size_t ws_size,
                              hipStream_t stream)
{
    const float* x       = (const float*)d_in[0];
    const int*   ei      = (const int*)d_in[1];      // int32 per harness contract
    const float* W       = (const float*)d_in[2];
    const float* att_src = (const float*)d_in[3];
    const float* att_dst = (const float*)d_in[4];
    const float* bias    = (const float*)d_in[5];
    float*       out     = (float*)d_out;

    const int N = in_sizes[0] / 128;   // 100000
    const int E = in_sizes[1] / 2;     // 1600000

    __hip_bfloat16* h      = (__hip_bfloat16*)d_ws;
    float*          a_s    = (float*)(h + (size_t)N * 64);
    float*          a_d    = a_s + N;
    int*            offc   = (int*)(a_d + N);                 // 263424 ints
    unsigned*       binned = (unsigned*)(offc + NCHUNK * (MAXB + 1));

    const int CE = (E + NCHUNK - 1) / NCHUNK;   // 6250 edges per chunk (<= CEMAX)
    const int NB = (N + BNODES - 1) >> BSH;     // 782 agg buckets
    const int nb_lin = (N + 127) / 128;         // 782 linear blocks

    k_fused<<<nb_lin + NCHUNK, 512, 0, stream>>>(x, W, att_src, att_dst,
                                                 h, a_s, a_d, ei, binned, offc,
                                                 N, E, CE, nb_lin);
    k_agg  <<<NB,              512, 0, stream>>>(binned, offc, a_s, a_d, h,
                                                 bias, out, N, CE);
}

// Round 9
// 163.966 us; speedup vs baseline: 2.0338x; 2.0338x over previous
//
#include <hip/hip_runtime.h>
#include <hip/hip_bf16.h>
#include <math.h>

#define NEG_SLOPE 0.2f
#define BSH    7          // log2(nodes per bucket)
#define BNODES 128        // nodes per bucket
#define CAP    2560       // max edges per bucket in LDS (mean 2048, 11 sigma)
#define MAXB   1024       // bucket count (covers up to 131072 nodes)
#define NCHUNK 256        // partition chunks
#define CEMAX  6272       // max edges per chunk staged in LDS (CE = 6250)
#define SMEMB  37376      // fused-kernel LDS bytes: part path 37376 > linear 16384

typedef __attribute__((ext_vector_type(8))) short bf16x8;
typedef __attribute__((ext_vector_type(4))) float f32x4;

__device__ __forceinline__ float leaky(float v) { return v >= 0.0f ? v : NEG_SLOPE * v; }
__device__ __forceinline__ int clampi(int v, int lo, int hi) {
    return v < lo ? lo : (v > hi ? hi : v);
}
// decode packed bf16 pair (low word / high word of a uint)
__device__ __forceinline__ float bflo(unsigned u) { return __uint_as_float(u << 16); }
__device__ __forceinline__ float bfhi(unsigned u) { return __uint_as_float(u & 0xFFFF0000u); }
// fp32 -> bf16 round-to-nearest-even
__device__ __forceinline__ unsigned short f2bf(float f) {
    unsigned u = __float_as_uint(f);
    return (unsigned short)((u + 0x7FFFu + ((u >> 16) & 1u)) >> 16);
}
__device__ __forceinline__ bf16x8 pack8(float4 a, float4 b) {
    bf16x8 r;
    r[0] = (short)f2bf(a.x); r[1] = (short)f2bf(a.y);
    r[2] = (short)f2bf(a.z); r[3] = (short)f2bf(a.w);
    r[4] = (short)f2bf(b.x); r[5] = (short)f2bf(b.y);
    r[6] = (short)f2bf(b.z); r[7] = (short)f2bf(b.w);
    return r;
}
// bijective XCD-chunked swizzle (m204): consecutive buckets land on one XCD
__device__ __forceinline__ int xcd_swz(int orig, int nwg) {
    int xcd = orig & 7;
    int i   = orig >> 3;
    int qq  = nwg >> 3, rr = nwg & 7;
    int base = (xcd < rr) ? xcd * (qq + 1) : rr * (qq + 1) + (xcd - rr) * qq;
    return base + i;
}

// K1 (fused): blocks [0, nb_lin) = MFMA linear+epilogue; blocks
// [nb_lin, nb_lin+NCHUNK) = chunk-local edge binning. Data-independent halves
// run concurrently. Wave-0 shfl scan (round 6). Unchanged this round.
__global__ __launch_bounds__(512) void k_fused(
    const float* __restrict__ x, const float* __restrict__ W,
    const float* __restrict__ att_src, const float* __restrict__ att_dst,
    __hip_bfloat16* __restrict__ h, float* __restrict__ a_s,
    float* __restrict__ a_d, const int* __restrict__ ei,
    unsigned* __restrict__ binned, int* __restrict__ offc,
    int N, int E, int CE, int nb_lin)
{
    __shared__ int4 smem4[SMEMB / 16];
    const int tid = threadIdx.x;

    if ((int)blockIdx.x < nb_lin) {
        short* wlds = (short*)smem4;      // 16 frag-sets x 64 lanes x 8 bf16

        for (int idx = tid; idx < 1024; idx += 512) {
            int f = idx >> 6, L = idx & 63;
            int t = f >> 2, k0i = f & 3;
            int kbase = k0i * 32 + (L >> 4) * 8;
            int c = t * 16 + (L & 15);
            unsigned short v[8];
#pragma unroll
            for (int j = 0; j < 8; ++j) v[j] = f2bf(W[(kbase + j) * 64 + c]);
            uint4 p;
            p.x = (unsigned)v[0] | ((unsigned)v[1] << 16);
            p.y = (unsigned)v[2] | ((unsigned)v[3] << 16);
            p.z = (unsigned)v[4] | ((unsigned)v[5] << 16);
            p.w = (unsigned)v[6] | ((unsigned)v[7] << 16);
            ((uint4*)wlds)[idx] = p;
        }
        __syncthreads();

        const int lane = tid & 63;
        const int w    = tid >> 6;
        const int base = blockIdx.x * 128 + w * 16;
        const int m    = lane & 15;
        const int quad = lane >> 4;

        int rowc = min(base + m, N - 1);
        const float4* xr = (const float4*)x + (size_t)rowc * 32;

        bf16x8 afrag[4];
#pragma unroll
        for (int k0i = 0; k0i < 4; ++k0i) {
            float4 f0 = xr[k0i * 8 + quad * 2 + 0];
            float4 f1 = xr[k0i * 8 + quad * 2 + 1];
            afrag[k0i] = pack8(f0, f1);
        }

        f32x4 acc[4];
#pragma unroll
        for (int t = 0; t < 4; ++t) acc[t] = (f32x4){0.f, 0.f, 0.f, 0.f};

        const bf16x8* wf = (const bf16x8*)wlds;
#pragma unroll
        for (int t = 0; t < 4; ++t) {
#pragma unroll
            for (int k0i = 0; k0i < 4; ++k0i) {
                bf16x8 bfr = wf[(t * 4 + k0i) * 64 + lane];
                acc[t] = __builtin_amdgcn_mfma_f32_16x16x32_bf16(afrag[k0i], bfr, acc[t], 0, 0, 0);
            }
        }

        float ps[4] = {0.f, 0.f, 0.f, 0.f};
        float pd[4] = {0.f, 0.f, 0.f, 0.f};
#pragma unroll
        for (int t = 0; t < 4; ++t) {
            float as_c = att_src[t * 16 + m];
            float ad_c = att_dst[t * 16 + m];
#pragma unroll
            for (int q = 0; q < 4; ++q) {
                ps[q] = fmaf(acc[t][q], as_c, ps[q]);
                pd[q] = fmaf(acc[t][q], ad_c, pd[q]);
            }
        }
#pragma unroll
        for (int t = 0; t < 4; ++t) {
#pragma unroll
            for (int q = 0; q < 4; ++q) {
                int n = base + quad * 4 + q;
                if (n < N) h[(size_t)n * 64 + t * 16 + m] = __float2bfloat16(acc[t][q]);
            }
        }
#pragma unroll
        for (int q = 0; q < 4; ++q) {
            ps[q] += __shfl_xor(ps[q], 1, 64);
            ps[q] += __shfl_xor(ps[q], 2, 64);
            ps[q] += __shfl_xor(ps[q], 4, 64);
            ps[q] += __shfl_xor(ps[q], 8, 64);
            pd[q] += __shfl_xor(pd[q], 1, 64);
            pd[q] += __shfl_xor(pd[q], 2, 64);
            pd[q] += __shfl_xor(pd[q], 4, 64);
            pd[q] += __shfl_xor(pd[q], 8, 64);
        }
        if (m == 0) {
#pragma unroll
            for (int q = 0; q < 4; ++q) {
                int n = base + quad * 4 + q;
                if (n < N) { a_s[n] = ps[q]; a_d[n] = pd[q]; }
            }
        }
    } else {
        int* hist = (int*)smem4;              // 1024
        int* off  = hist + MAXB;              // 1024
        int* cur  = off + MAXB;               // 1024
        unsigned* stage = (unsigned*)(cur + MAXB);  // CEMAX

        const int c  = (int)blockIdx.x - nb_lin;
        const int e0 = c * CE;
        const int e1 = min(E, e0 + CE);
        const int ne = e1 - e0;

        for (int i = tid; i < MAXB; i += 512) hist[i] = 0;
        __syncthreads();
        for (int e = e0 + tid; e < e1; e += 512) {
            int dst = clampi(ei[E + e], 0, N - 1);
            atomicAdd(&hist[dst >> BSH], 1);
        }
        __syncthreads();
        // wave 0: exclusive scan of hist[0..1023] -> off, cur (no barriers)
        if (tid < 64) {
            int v[16]; int tsum = 0;
#pragma unroll
            for (int k = 0; k < 16; ++k) { v[k] = hist[tid * 16 + k]; tsum += v[k]; }
            int incl = tsum;
#pragma unroll
            for (int d = 1; d < 64; d <<= 1) {
                int t = __shfl_up(incl, d, 64);
                if (tid >= d) incl += t;
            }
            int run = incl - tsum;
#pragma unroll
            for (int k = 0; k < 16; ++k) {
                off[tid * 16 + k] = run;
                cur[tid * 16 + k] = run;
                run += v[k];
            }
        }
        __syncthreads();
        for (int e = e0 + tid; e < e1; e += 512) {
            int src = clampi(ei[e],     0, N - 1);
            int dst = clampi(ei[E + e], 0, N - 1);
            int pos = atomicAdd(&cur[dst >> BSH], 1);
            stage[clampi(pos, 0, CEMAX - 1)] =
                ((unsigned)(dst & (BNODES - 1)) << 17) | (unsigned)src;
        }
        __syncthreads();
        for (int i = tid; i < ne; i += 512) binned[e0 + i] = stage[i];
        int* oc = offc + (size_t)c * (MAXB + 1);
        for (int i = tid; i < MAXB; i += 512) oc[i] = off[i];
        if (tid == 0) oc[MAXB] = ne;
    }
}

// K2: one block (512 threads, 8 waves) per 128-node bucket.
// Round 9 = round-6 structure + ONE change in the Phase-B loop: the ew entry
// is carried one iteration ahead in a register, so the h-gather address is
// register-resident at the top of each iteration (the ds_read no longer sits
// on the gather's critical path). r8's sched_barrier forcing is removed
// (it spilled: WRITE 25->386 MB); this variant adds only ~3 loop-carried
// VGPRs and cannot be sunk (the LDS load feeds the NEXT iter's first use).
__global__ __launch_bounds__(512, 8) void k_agg(
    const unsigned* __restrict__ binned, const int* __restrict__ offc,
    const float* __restrict__ a_s, const float* __restrict__ a_d,
    const __hip_bfloat16* __restrict__ hm, const float* __restrict__ bias,
    float* __restrict__ out, int N, int CE)
{
    __shared__ int   cnt[BNODES];
    __shared__ int   st[BNODES];
    __shared__ int   cur[BNODES];
    __shared__ float lsum[BNODES];
    __shared__ float wsl[BNODES];
    __shared__ float adl[BNODES];
    __shared__ int   runScan[NCHUNK + 1];
    __shared__ int   gbase[NCHUNK];
    __shared__ unsigned eraw[CAP];
    __shared__ uint2 ew[CAP];          // .x = src node, .y = f32 bits of w

    const int tid   = threadIdx.x;
    const int b     = xcd_swz((int)blockIdx.x, (int)gridDim.x);
    const int nbase = b << BSH;

    if (tid < BNODES) {
        cnt[tid] = 0;
        int n = nbase + tid;
        float as = 0.f, ad = 0.f;
        if (n < N) { as = a_s[n]; ad = a_d[n]; }
        adl[tid] = ad;
        float v = (n < N) ? __expf(leaky(as + ad)) : 0.f;
        wsl[tid]  = v;                 // self-loop weight
        lsum[tid] = v;                 // denominator starts with self loop
    }
    if (tid < NCHUNK) {
        const int* oc = offc + (size_t)tid * (MAXB + 1);
        int o0 = clampi(oc[b],     0, CE);
        int o1 = clampi(oc[b + 1], o0, CE);
        gbase[tid]   = tid * CE + o0;
        runScan[tid] = o1 - o0;        // run length (scanned below)
    }
    __syncthreads();                                   // B1
    // wave 0: exclusive scan of runScan[0..255] in registers
    if (tid < 64) {
        int v0 = runScan[tid * 4 + 0], v1 = runScan[tid * 4 + 1];
        int v2 = runScan[tid * 4 + 2], v3 = runScan[tid * 4 + 3];
        int tsum = v0 + v1 + v2 + v3;
        int incl = tsum;
#pragma unroll
        for (int d = 1; d < 64; d <<= 1) {
            int t = __shfl_up(incl, d, 64);
            if (tid >= d) incl += t;
        }
        int excl = incl - tsum;
        runScan[tid * 4 + 0] = excl;
        runScan[tid * 4 + 1] = excl + v0;
        runScan[tid * 4 + 2] = excl + v0 + v1;
        runScan[tid * 4 + 3] = excl + v0 + v1 + v2;
        if (tid == 63) runScan[NCHUNK] = incl;
    }
    __syncthreads();                                   // B2
    int n_e = runScan[NCHUNK];
    if (n_e > CAP) n_e = CAP;          // statistically never

    // fused: coalesced copy (binary search chunk map) + node histogram
    for (int i = tid; i < n_e; i += 512) {
        int c = 0;
#pragma unroll
        for (int stp = NCHUNK >> 1; stp >= 1; stp >>= 1)
            if (runScan[c + stp] <= i) c += stp;
        unsigned pk = binned[(size_t)gbase[c] + (i - runScan[c])];
        eraw[i] = pk;
        atomicAdd(&cnt[(pk >> 17) & (BNODES - 1)], 1);
    }
    __syncthreads();                                   // B3
    // wave 0: exclusive scan of cnt[0..127] -> st, cur
    if (tid < 64) {
        int v0 = cnt[tid * 2], v1 = cnt[tid * 2 + 1];
        int tsum = v0 + v1;
        int incl = tsum;
#pragma unroll
        for (int d = 1; d < 64; d <<= 1) {
            int t = __shfl_up(incl, d, 64);
            if (tid >= d) incl += t;
        }
        int excl = incl - tsum;
        st[tid * 2]      = excl;      cur[tid * 2]      = excl;
        st[tid * 2 + 1]  = excl + v0; cur[tid * 2 + 1]  = excl + v0;
    }
    __syncthreads();                                   // B4
    // scatter + fused attention weight + denominator (LDS -> LDS)
    for (int i = tid; i < n_e; i += 512) {
        unsigned pk = eraw[i];
        int ld  = (int)(pk >> 17) & (BNODES - 1);
        int src = (int)(pk & 0x1FFFFu);
        float wv = __expf(leaky(a_s[src] + adl[ld]));
        int pos = atomicAdd(&cur[ld], 1);
        if (pos < CAP) ew[pos] = make_uint2((unsigned)src, __float_as_uint(wv));
        atomicAdd(&lsum[ld], wv);
    }
    __syncthreads();                                   // B5

    // Phase B: lane = (node-slot p = lane>>3, octet q = lane&7)
    const int lane = tid & 63;
    const int w    = tid >> 6;       // wave 0..7
    const int q    = lane & 7;       // feature octet: features 8q..8q+7
    const int p    = lane >> 3;      // node slot 0..7
    const uint4*  h4 = (const uint4*)hm;
    const float4* b4 = (const float4*)bias;
    const float4 bb0 = b4[2 * q];
    const float4 bb1 = b4[2 * q + 1];

#pragma unroll 1
    for (int t = 0; t < 2; ++t) {
        int ln = t * 64 + w * 8 + p;
        int n  = nbase + ln;
        if (n >= N) continue;
        int deg = cnt[ln];
        int s0  = st[ln];
        if (s0 > CAP) s0 = CAP;            // defensive (never in practice)
        if (deg > CAP - s0) deg = CAP - s0;

        // self-loop contribution (each lane owns its octet exactly once)
        float wself = wsl[ln];
        uint4 U = h4[(size_t)n * 8 + q];
        float acc0 = wself * bflo(U.x), acc1 = wself * bfhi(U.x);
        float acc2 = wself * bflo(U.y), acc3 = wself * bfhi(U.y);
        float acc4 = wself * bflo(U.z), acc5 = wself * bfhi(U.z);
        float acc6 = wself * bflo(U.w), acc7 = wself * bfhi(U.w);

        // depth-1 VMEM pipeline with register-carried ew lookahead:
        // eB holds entry j+1 so the gather for j+1 issues from a register
        // address at the top of iter j; the ds_read fetches entry j+2.
        float wc = 0.f;
        uint2 eB = make_uint2(0u, 0u);
        if (deg > 0) {
            uint2 eA = ew[s0];
            wc = __uint_as_float(eA.y);
            U  = h4[(size_t)eA.x * 8 + q];
        }
        if (deg > 1) eB = ew[s0 + 1];
        for (int j = 0; j < deg; ++j) {
            uint4 U2 = make_uint4(0u, 0u, 0u, 0u);
            float w2 = 0.f;
            if (j + 1 < deg) {                  // gather j+1: addr from reg
                w2 = __uint_as_float(eB.y);
                U2 = h4[(size_t)eB.x * 8 + q];
            }
            uint2 eC = make_uint2(0u, 0u);
            if (j + 2 < deg) eC = ew[s0 + j + 2];   // LDS read for j+2
            acc0 = fmaf(wc, bflo(U.x), acc0);
            acc1 = fmaf(wc, bfhi(U.x), acc1);
            acc2 = fmaf(wc, bflo(U.y), acc2);
            acc3 = fmaf(wc, bfhi(U.y), acc3);
            acc4 = fmaf(wc, bflo(U.z), acc4);
            acc5 = fmaf(wc, bfhi(U.z), acc5);
            acc6 = fmaf(wc, bflo(U.w), acc6);
            acc7 = fmaf(wc, bfhi(U.w), acc7);
            U = U2; wc = w2; eB = eC;
        }

        float inv = 1.0f / lsum[ln];
        float4 o0, o1;
        o0.x = bb0.x + acc0 * inv;
        o0.y = bb0.y + acc1 * inv;
        o0.z = bb0.z + acc2 * inv;
        o0.w = bb0.w + acc3 * inv;
        o1.x = bb1.x + acc4 * inv;
        o1.y = bb1.y + acc5 * inv;
        o1.z = bb1.z + acc6 * inv;
        o1.w = bb1.w + acc7 * inv;
        float4* o4 = (float4*)out;
        o4[(size_t)n * 16 + 2 * q + 0] = o0;
        o4[(size_t)n * 16 + 2 * q + 1] = o1;
    }
}

extern "C" void kernel_launch(void* const* d_in, const int* in_sizes, int n_in,
                              void* d_out, int out_size, void* d_ws, size_t ws_size,
                              hipStream_t stream)
{
    const float* x       = (const float*)d_in[0];
    const int*   ei      = (const int*)d_in[1];      // int32 per harness contract
    const float* W       = (const float*)d_in[2];
    const float* att_src = (const float*)d_in[3];
    const float* att_dst = (const float*)d_in[4];
    const float* bias    = (const float*)d_in[5];
    float*       out     = (float*)d_out;

    const int N = in_sizes[0] / 128;   // 100000
    const int E = in_sizes[1] / 2;     // 1600000

    __hip_bfloat16* h      = (__hip_bfloat16*)d_ws;
    float*          a_s    = (float*)(h + (size_t)N * 64);
    float*          a_d    = a_s + N;
    int*            offc   = (int*)(a_d + N);                 // 263424 ints
    unsigned*       binned = (unsigned*)(offc + NCHUNK * (MAXB + 1));

    const int CE = (E + NCHUNK - 1) / NCHUNK;   // 6250 edges per chunk (<= CEMAX)
    const int NB = (N + BNODES - 1) >> BSH;     // 782 agg buckets
    const int nb_lin = (N + 127) / 128;         // 782 linear blocks

    k_fused<<<nb_lin + NCHUNK, 512, 0, stream>>>(x, W, att_src, att_dst,
                                                 h, a_s, a_d, ei, binned, offc,
                                                 N, E, CE, nb_lin);
    k_agg  <<<NB,              512, 0, stream>>>(binned, offc, a_s, a_d, h,
                                                 bias, out, N, CE);
}